// Round 1
// baseline (569.796 us; speedup 1.0000x reference)
//
#include <hip/hip_runtime.h>
#include <hip/hip_bf16.h>

#define IN_F 128
#define HID 16
#define OUT_F 64
#define XT_LD 132  // padded LDS stride for x tile (breaks 4-way bank conflict)

// ---------- dtype-flex helpers (device-side runtime dtype detection) ----------
__device__ __forceinline__ float loadF(const void* p, size_t i, int bf) {
  if (bf) {
    unsigned v = ((unsigned)((const unsigned short*)p)[i]) << 16;
    float f; __builtin_memcpy(&f, &v, 4); return f;
  }
  return ((const float*)p)[i];
}
__device__ __forceinline__ int loadE(const void* p, size_t i, int i64) {
  if (i64) return (int)((const long long*)p)[i];
  return ((const int*)p)[i];
}

// flags[0] = 1 if float tensors are bf16; flags[1] = 1 if edge_index is int64
__global__ void k_detect(const void* x, const void* ei, int* flags) {
  __shared__ int c_ok, c_hi;
  int t = threadIdx.x;
  if (t == 0) { c_ok = 0; c_hi = 0; }
  __syncthreads();
  const float* xf = (const float*)x;
  int ok = 0;
  for (int i = t; i < 1024; i += 256) {
    float v = fabsf(xf[i]);
    if (v > 1e-4f && v < 1e4f) ok++;   // N(0,1) f32 passes ~always; packed bf16 ~never
  }
  const int* ep = (const int*)ei;
  int hi = 0;
  for (int i = t; i < 1024; i += 256)
    if (ep[2*i + 1] != 0) hi++;        // int64 node ids < 2^31 -> high words all zero
  atomicAdd(&c_ok, ok);
  atomicAdd(&c_hi, hi);
  __syncthreads();
  if (t == 0) {
    flags[0] = (c_ok < 512) ? 1 : 0;
    flags[1] = (c_hi == 0) ? 1 : 0;
  }
}

// ---------- degree / normalization ----------
__global__ void k_init_deg(unsigned* deg, int n) {
  int i = blockIdx.x * 256 + threadIdx.x;
  if (i < n) deg[i] = 1u;  // self-loop
}
__global__ void k_count(const void* ei, const int* flags, unsigned* deg, int e) {
  int i = blockIdx.x * 256 + threadIdx.x;
  if (i >= e) return;
  int i64 = flags[1];
  int d = loadE(ei, (size_t)e + i, i64);
  atomicAdd(&deg[d], 1u);
}
__global__ void k_dinv(const unsigned* deg, float* dinv, int n) {
  int i = blockIdx.x * 256 + threadIdx.x;
  if (i < n) dinv[i] = rsqrtf((float)deg[i]);
}

// ---------- prefix sum over in-edge counts (deg-1), 3-kernel scan ----------
__global__ void k_ps1(const unsigned* deg, unsigned* part, int n) {
  __shared__ unsigned s[256];
  int b = blockIdx.x, t = threadIdx.x;
  unsigned sum = 0;
  int base = b * 1024 + t * 4;
  for (int j = 0; j < 4; j++) {
    int i = base + j;
    if (i < n) sum += deg[i] - 1u;
  }
  s[t] = sum; __syncthreads();
  for (int d = 128; d > 0; d >>= 1) {
    if (t < d) s[t] += s[t + d];
    __syncthreads();
  }
  if (t == 0) part[b] = s[0];
}
__global__ void k_ps2(const unsigned* part, unsigned* basep, int nb) {
  if (threadIdx.x == 0) {
    unsigned run = 0;
    for (int b = 0; b < nb; b++) { basep[b] = run; run += part[b]; }
  }
}
__global__ void k_ps3(const unsigned* deg, const unsigned* basep,
                      unsigned* offs, unsigned* cur, int n) {
  __shared__ unsigned ts[256];
  int b = blockIdx.x, t = threadIdx.x;
  int base = b * 1024 + t * 4;
  unsigned c[4]; unsigned sum = 0;
  for (int j = 0; j < 4; j++) {
    int i = base + j;
    c[j] = (i < n) ? deg[i] - 1u : 0u;
    sum += c[j];
  }
  ts[t] = sum; __syncthreads();
  for (int d = 1; d < 256; d <<= 1) {
    unsigned a = (t >= d) ? ts[t - d] : 0u;
    __syncthreads();
    ts[t] += a;
    __syncthreads();
  }
  unsigned run = ts[t] - sum + basep[b];
  for (int j = 0; j < 4; j++) {
    int i = base + j;
    if (i < n) { offs[i] = run; cur[i] = run; run += c[j]; }
  }
}

// ---------- CSR fill (by destination) ----------
__global__ void k_fill(const void* ei, const int* flags, unsigned* cur,
                       unsigned* csr, int e) {
  int i = blockIdx.x * 256 + threadIdx.x;
  if (i >= e) return;
  int i64 = flags[1];
  int s = loadE(ei, i, i64);
  int d = loadE(ei, (size_t)e + i, i64);
  unsigned pos = atomicAdd(&cur[d], 1u);
  csr[pos] = (unsigned)s;
}

// ---------- hs1 = dinv[n] * (x @ W1) ----------
__global__ __launch_bounds__(256) void k_xw1(const void* x, const void* W1,
                                             const int* flags, const float* dinv,
                                             float* hs1, int n) {
  __shared__ float w[IN_F * HID];
  __shared__ float xt[16 * XT_LD];
  const int t = threadIdx.x;
  const int bf = flags[0];
  for (int i = t; i < IN_F * HID; i += 256) w[i] = loadF(W1, i, bf);
  const int n0 = blockIdx.x * 16;
  for (int i = t; i < 16 * IN_F; i += 256) {
    int rl = i >> 7, k = i & 127;
    int row = n0 + rl;
    xt[rl * XT_LD + k] = (row < n) ? loadF(x, (size_t)row * IN_F + k, bf) : 0.f;
  }
  __syncthreads();
  const int ln = t >> 4, c = t & 15;
  const int node = n0 + ln;
  if (node >= n) return;
  float acc = 0.f;
  #pragma unroll 16
  for (int k = 0; k < IN_F; ++k)
    acc = fmaf(xt[ln * XT_LD + k], w[k * HID + c], acc);
  hs1[(size_t)node * HID + c] = dinv[node] * acc;
}

// ---------- layer-1 aggregation: hd = dinv * relu(dinv*(sum hs1[src] + hs1[self]) + b1) ----------
__global__ __launch_bounds__(256) void k_agg1(const unsigned* csr, const unsigned* offs,
                                              const unsigned* deg, const float* dinv,
                                              const float* hs1, const void* b1,
                                              const int* flags, float* hd, int n) {
  const int wid = (blockIdx.x * 256 + threadIdx.x) >> 6;
  if (wid >= n) return;
  const int lane = threadIdx.x & 63;
  const int sub = lane >> 2, ch = lane & 3;
  const unsigned off = offs[wid];
  const unsigned cnt = deg[wid] - 1u;
  float4 acc = make_float4(0.f, 0.f, 0.f, 0.f);
  for (unsigned i = sub; i < cnt; i += 16) {
    unsigned s = csr[off + i];
    const float4 v = ((const float4*)(hs1 + (size_t)s * HID))[ch];
    acc.x += v.x; acc.y += v.y; acc.z += v.z; acc.w += v.w;
  }
  #pragma unroll
  for (int m = 4; m < 64; m <<= 1) {
    acc.x += __shfl_xor(acc.x, m, 64);
    acc.y += __shfl_xor(acc.y, m, 64);
    acc.z += __shfl_xor(acc.z, m, 64);
    acc.w += __shfl_xor(acc.w, m, 64);
  }
  if (lane < 4) {
    const float di = dinv[wid];
    const float4 sv = ((const float4*)(hs1 + (size_t)wid * HID))[ch];
    const int bf = flags[0];
    float4 o;
    o.x = di * fmaxf(fmaf(di, acc.x + sv.x, loadF(b1, ch * 4 + 0, bf)), 0.f);
    o.y = di * fmaxf(fmaf(di, acc.y + sv.y, loadF(b1, ch * 4 + 1, bf)), 0.f);
    o.z = di * fmaxf(fmaf(di, acc.z + sv.z, loadF(b1, ch * 4 + 2, bf)), 0.f);
    o.w = di * fmaxf(fmaf(di, acc.w + sv.w, loadF(b1, ch * 4 + 3, bf)), 0.f);
    ((float4*)(hd + (size_t)wid * HID))[ch] = o;
  }
}

// ---------- layer-2 aggregation + fused 16->64 transform + relu ----------
__global__ __launch_bounds__(256) void k_agg2(const unsigned* csr, const unsigned* offs,
                                              const unsigned* deg, const float* dinv,
                                              const float* hd, const void* W2,
                                              const void* b2, const int* flags,
                                              void* out, int n) {
  __shared__ float w2s[HID * OUT_F];
  const int t = threadIdx.x;
  const int bf = flags[0];
  for (int i = t; i < HID * OUT_F; i += 256) w2s[i] = loadF(W2, i, bf);
  __syncthreads();
  const int wid = (blockIdx.x * 256 + t) >> 6;
  if (wid >= n) return;
  const int lane = t & 63;
  const int sub = lane >> 2, ch = lane & 3;
  const unsigned off = offs[wid];
  const unsigned cnt = deg[wid] - 1u;
  float4 acc = make_float4(0.f, 0.f, 0.f, 0.f);
  for (unsigned i = sub; i < cnt; i += 16) {
    unsigned s = csr[off + i];
    const float4 v = ((const float4*)(hd + (size_t)s * HID))[ch];
    acc.x += v.x; acc.y += v.y; acc.z += v.z; acc.w += v.w;
  }
  #pragma unroll
  for (int m = 4; m < 64; m <<= 1) {
    acc.x += __shfl_xor(acc.x, m, 64);
    acc.y += __shfl_xor(acc.y, m, 64);
    acc.z += __shfl_xor(acc.z, m, 64);
    acc.w += __shfl_xor(acc.w, m, 64);
  }
  const float di = dinv[wid];
  const float4 sv = ((const float4*)(hd + (size_t)wid * HID))[ch];
  acc.x = di * (acc.x + sv.x);
  acc.y = di * (acc.y + sv.y);
  acc.z = di * (acc.z + sv.z);
  acc.w = di * (acc.w + sv.w);
  float a[16];
  #pragma unroll
  for (int j = 0; j < 4; ++j) {
    a[4 * j + 0] = __shfl(acc.x, j, 64);
    a[4 * j + 1] = __shfl(acc.y, j, 64);
    a[4 * j + 2] = __shfl(acc.z, j, 64);
    a[4 * j + 3] = __shfl(acc.w, j, 64);
  }
  float o = loadF(b2, lane, bf);
  #pragma unroll
  for (int k = 0; k < HID; ++k) o = fmaf(a[k], w2s[k * OUT_F + lane], o);
  o = fmaxf(o, 0.f);
  size_t oi = (size_t)wid * OUT_F + lane;
  if (bf) ((__hip_bfloat16*)out)[oi] = __float2bfloat16(o);
  else    ((float*)out)[oi] = o;
}

extern "C" void kernel_launch(void* const* d_in, const int* in_sizes, int n_in,
                              void* d_out, int out_size, void* d_ws, size_t ws_size,
                              hipStream_t stream) {
  const void* x  = d_in[0];
  const void* ei = d_in[1];
  const void* W1 = d_in[2];
  const void* b1 = d_in[3];
  const void* W2 = d_in[4];
  const void* b2 = d_in[5];
  const int n = in_sizes[0] / IN_F;
  const int e = in_sizes[1] / 2;

  char* p = (char*)d_ws;
  auto alloc = [&](size_t bytes) -> char* {
    char* r = p;
    p += (bytes + 255) & ~(size_t)255;
    return r;
  };
  int*      flags = (int*)alloc(256);
  unsigned* deg   = (unsigned*)alloc((size_t)n * 4);
  float*    dinv  = (float*)alloc((size_t)n * 4);
  unsigned* offs  = (unsigned*)alloc((size_t)n * 4);
  unsigned* cur   = (unsigned*)alloc((size_t)n * 4);
  unsigned* part  = (unsigned*)alloc(4096);
  unsigned* basep = (unsigned*)alloc(4096);
  unsigned* csr   = (unsigned*)alloc((size_t)e * 4);
  float*    hs1   = (float*)alloc((size_t)n * HID * 4);
  float*    hd    = (float*)alloc((size_t)n * HID * 4);

  const int nbN = (n + 255) / 256;
  const int nbE = (e + 255) / 256;
  const int nbS = (n + 1023) / 1024;

  k_detect<<<1, 256, 0, stream>>>(x, ei, flags);
  k_init_deg<<<nbN, 256, 0, stream>>>(deg, n);
  k_count<<<nbE, 256, 0, stream>>>(ei, flags, deg, e);
  k_dinv<<<nbN, 256, 0, stream>>>(deg, dinv, n);
  k_ps1<<<nbS, 256, 0, stream>>>(deg, part, n);
  k_ps2<<<1, 64, 0, stream>>>(part, basep, nbS);
  k_ps3<<<nbS, 256, 0, stream>>>(deg, basep, offs, cur, n);
  k_fill<<<nbE, 256, 0, stream>>>(ei, flags, cur, csr, e);
  k_xw1<<<(n + 15) / 16, 256, 0, stream>>>(x, W1, flags, dinv, hs1, n);
  k_agg1<<<(n + 3) / 4, 256, 0, stream>>>(csr, offs, deg, dinv, hs1, b1, flags, hd, n);
  k_agg2<<<(n + 3) / 4, 256, 0, stream>>>(csr, offs, deg, dinv, hd, W2, b2, flags, d_out, n);
}